// Round 12
// baseline (87.837 us; speedup 1.0000x reference)
//
#include <hip/hip_runtime.h>
#include <cfloat>
#include <math.h>

#define NB 1024            // norm bins
#define NORM_RANGE 5.0f    // bin range [0, 5); larger norms clamp into top bin
#define QG 64              // queries per block (one wave)
#define RBLOCK 256

__device__ __forceinline__ int norm_bin(float n) {
    int b = (int)(n * ((float)NB / NORM_RANGE));
    return min(max(b, 0), NB - 1);
}

// ---- K1: zero hists, init P to +inf ----
__global__ __launch_bounds__(256) void init_kernel(
    int* hist1, int* hist2, unsigned int* P1, int N, unsigned int* P2, int M)
{
    const int i = blockIdx.x * 256 + threadIdx.x;
    if (i < NB) { hist1[i] = 0; hist2[i] = 0; }
    if (i < N) P1[i] = 0x7F800000u;
    {
        const int j = i - N;
        if (j >= 0 && j < M) P2[j] = 0x7F800000u;
    }
}

// ---- K2: histogram of norms, both clouds ----
__global__ __launch_bounds__(256) void hist_kernel(
    const float* __restrict__ pc1, int N, const float* __restrict__ pc2, int M,
    int* hist1, int* hist2)
{
    const int i = blockIdx.x * 256 + threadIdx.x;
    const float* src; int* h; int j;
    if (i < N) { src = pc1; h = hist1; j = i; }
    else if (i < N + M) { src = pc2; h = hist2; j = i - N; }
    else return;
    const float x = src[3 * j], y = src[3 * j + 1], z = src[3 * j + 2];
    const float n = sqrtf(fmaf(x, x, fmaf(y, y, z * z)));
    atomicAdd(&h[norm_bin(n)], 1);
}

// ---- K3: exclusive prefix over both hists -> start & cursor arrays ----
__global__ __launch_bounds__(NB) void scan_kernel(
    const int* __restrict__ hist1, const int* __restrict__ hist2,
    int* start1, int* start2, int* cur1, int* cur2)
{
    __shared__ int buf[NB];
    const int tid = threadIdx.x;
    for (int pass = 0; pass < 2; ++pass) {
        const int* h = pass ? hist2 : hist1;
        int* st = pass ? start2 : start1;
        int* cu = pass ? cur2 : cur1;
        const int v = h[tid];
        buf[tid] = v;
        __syncthreads();
        for (int off = 1; off < NB; off <<= 1) {
            const int add = (tid >= off) ? buf[tid - off] : 0;
            __syncthreads();
            buf[tid] += add;
            __syncthreads();
        }
        const int incl = buf[tid];
        const int excl = incl - v;
        st[tid] = excl;
        cu[tid] = excl;
        if (tid == NB - 1) st[NB] = incl;
        __syncthreads();
    }
}

// ---- K4: scatter points into norm-sorted (by bin) arrays ----
// S = {x, y, z, h=0.5*|p|^2}; nrm = |p|; idx = original index.
// Order within a bin is nondeterministic (atomic cursor) but all consumers
// are order-independent (exact min over a set).
__global__ __launch_bounds__(256) void scatter_kernel(
    const float* __restrict__ pc1, int N, const float* __restrict__ pc2, int M,
    int* cur1, int* cur2,
    float4* S1, float* nrm1, int* idx1,
    float4* S2, float* nrm2, int* idx2)
{
    const int i = blockIdx.x * 256 + threadIdx.x;
    const float* src; int* cu; float4* S; float* nr; int* ix; int j;
    if (i < N) { src = pc1; cu = cur1; S = S1; nr = nrm1; ix = idx1; j = i; }
    else if (i < N + M) { src = pc2; cu = cur2; S = S2; nr = nrm2; ix = idx2; j = i - N; }
    else return;
    const float x = src[3 * j], y = src[3 * j + 1], z = src[3 * j + 2];
    const float n2 = fmaf(x, x, fmaf(y, y, z * z));
    const float n = sqrtf(n2);
    const int pos = atomicAdd(&cu[norm_bin(n)], 1);
    S[pos] = make_float4(x, y, z, 0.5f * n2);
    nr[pos] = n;
    ix[pos] = j;
}

// ---- K5: pruned NN scan ----
// grid: (qgroups, 2 scan-dirs up/down, 2 cloud-dirs). 64-thread (1-wave)
// blocks; each lane owns one norm-sorted query. Scan the norm-sorted
// candidate array outward from the query group's norm position in
// 64-candidate LDS tiles. Terminate a direction when the bin-edge bound
// proves (nb-na)^2 > best for ALL lanes (bin edges are safe under the
// top-bin clamp: lo-edge is always a valid lower bound; top bin's hi
// edge is +inf). Skipped candidates provably cannot improve the min ->
// result is the EXACT min, combined across up/down blocks via atomicMin.
__global__ __launch_bounds__(QG) void minscan_kernel(
    const float4* __restrict__ S1, const float* __restrict__ nrm1,
    const int* __restrict__ idx1, int N,
    const float4* __restrict__ S2, const float* __restrict__ nrm2,
    const int* __restrict__ idx2, int M,
    const int* __restrict__ start1, const int* __restrict__ start2,
    unsigned int* __restrict__ P1, unsigned int* __restrict__ P2)
{
    __shared__ float4 tile[QG];
    const int lane = threadIdx.x;
    const float W = NORM_RANGE / (float)NB;

    const float4* SQ; const float* NQ; const int* IQ; int Qn;
    const float4* SB; const float* NBn; const int* stB; int Bn;
    unsigned int* P;
    if (blockIdx.z == 0) { SQ=S1; NQ=nrm1; IQ=idx1; Qn=N; SB=S2; NBn=nrm2; stB=start2; Bn=M; P=P1; }
    else                 { SQ=S2; NQ=nrm2; IQ=idx2; Qn=M; SB=S1; NBn=nrm1; stB=start1; Bn=N; P=P2; }

    const int qbase = (int)blockIdx.x * QG;
    const int qi = min(qbase + lane, Qn - 1);
    const float4 q = SQ[qi];
    const float na = NQ[qi];
    const float nax = -q.x, nay = -q.y, naz = -q.z;
    const float a2 = 2.0f * q.w;

    const float nmid = NQ[min(qbase + QG / 2, Qn - 1)];
    const int cstart = stB[norm_bin(nmid)];

    float bestf = FLT_MAX;
    float r = FLT_MAX;

#define PROCESS_TILE() do { \
        _Pragma("unroll 8") \
        for (int j = 0; j < QG; j += 2) { \
            float4 b0 = tile[j], b1 = tile[j + 1]; \
            float f0 = fmaf(nax, b0.x, fmaf(nay, b0.y, fmaf(naz, b0.z, b0.w))); \
            float f1 = fmaf(nax, b1.x, fmaf(nay, b1.y, fmaf(naz, b1.z, b1.w))); \
            bestf = fminf(fminf(bestf, f0), f1); \
        } \
        float dcur = fmaxf(fmaf(2.0f, bestf, a2), 0.0f); \
        r = sqrtf(dcur) * 1.0001f + 1e-7f; \
    } while (0)

    if (blockIdx.y == 0) {
        // up-scan [cstart, Bn)
        for (int t = cstart; t < Bn; t += QG) {
            const float lo = (float)norm_bin(NBn[t]) * W;   // lower bound on all norms at idx >= t
            if (__all(lo - na > r)) break;
            __syncthreads();
            tile[lane] = SB[min(t + lane, Bn - 1)];
            __syncthreads();
            PROCESS_TILE();
        }
    } else {
        // down-scan [0, cstart)
        for (int thi = cstart; thi > 0; ) {
            const int kb = norm_bin(NBn[thi - 1]);
            const float hi = (kb >= NB - 1) ? FLT_MAX : (float)(kb + 1) * W;  // upper bound on norms at idx < thi
            if (__all(na - hi > r)) break;
            const int tlo = max(0, thi - QG);
            __syncthreads();
            tile[lane] = SB[min(tlo + lane, Bn - 1)];  // lanes past range dup real points: min-safe
            __syncthreads();
            PROCESS_TILE();
            thi = tlo;
        }
    }
#undef PROCESS_TILE

    float d = fmaxf(fmaf(2.0f, bestf, a2), 0.0f);
    atomicMin(&P[IQ[qi]], __float_as_uint(d));
}

// ---- K6/K7: mean(P1)/N + mean(P2)/M ----
__global__ __launch_bounds__(RBLOCK) void reduce1_kernel(
    const unsigned int* __restrict__ P1, int N,
    const unsigned int* __restrict__ P2, int M, double* __restrict__ bsum)
{
    const int tid = threadIdx.x;
    const int g = blockIdx.x * RBLOCK + tid;
    double s = 0.0;
    if (g < N) s = (double)__uint_as_float(P1[g]) / (double)N;
    else if (g < N + M) s = (double)__uint_as_float(P2[g - N]) / (double)M;
    for (int off = 32; off > 0; off >>= 1)
        s += __shfl_down(s, off, 64);
    __shared__ double wsum[RBLOCK / 64];
    if ((tid & 63) == 0) wsum[tid >> 6] = s;
    __syncthreads();
    if (tid == 0) {
        double tot = 0.0;
        #pragma unroll
        for (int w = 0; w < RBLOCK / 64; ++w) tot += wsum[w];
        bsum[blockIdx.x] = tot;
    }
}

__global__ __launch_bounds__(RBLOCK) void reduce2_kernel(
    const double* __restrict__ bsum, int nb, float* __restrict__ out)
{
    const int tid = threadIdx.x;
    double s = 0.0;
    for (int i = tid; i < nb; i += RBLOCK) s += bsum[i];
    for (int off = 32; off > 0; off >>= 1)
        s += __shfl_down(s, off, 64);
    __shared__ double wsum[RBLOCK / 64];
    if ((tid & 63) == 0) wsum[tid >> 6] = s;
    __syncthreads();
    if (tid == 0) {
        double tot = 0.0;
        #pragma unroll
        for (int w = 0; w < RBLOCK / 64; ++w) tot += wsum[w];
        out[0] = (float)tot;
    }
}

extern "C" void kernel_launch(void* const* d_in, const int* in_sizes, int n_in,
                              void* d_out, int out_size, void* d_ws, size_t ws_size,
                              hipStream_t stream) {
    const float* pc1 = (const float*)d_in[0];
    const float* pc2 = (const float*)d_in[1];
    const int N = in_sizes[0] / 3;
    const int M = in_sizes[1] / 3;
    float* out = (float*)d_out;

    // ws layout (16B-aligned first)
    char* w = (char*)d_ws;
    float4* S1 = (float4*)w;                 w += (size_t)N * 16;
    float4* S2 = (float4*)w;                 w += (size_t)M * 16;
    double* bsum = (double*)w;               w += 256 * 8;
    unsigned int* P1 = (unsigned int*)w;     w += (size_t)N * 4;
    unsigned int* P2 = (unsigned int*)w;     w += (size_t)M * 4;
    float* nrm1 = (float*)w;                 w += (size_t)N * 4;
    float* nrm2 = (float*)w;                 w += (size_t)M * 4;
    int* idx1 = (int*)w;                     w += (size_t)N * 4;
    int* idx2 = (int*)w;                     w += (size_t)M * 4;
    int* hist1 = (int*)w;                    w += NB * 4;
    int* hist2 = (int*)w;                    w += NB * 4;
    int* start1 = (int*)w;                   w += (NB + 1) * 4;
    int* start2 = (int*)w;                   w += (NB + 1) * 4;
    int* cur1 = (int*)w;                     w += NB * 4;
    int* cur2 = (int*)w;

    const int T = N + M;
    const int gp = (T + 255) / 256;
    init_kernel<<<gp, 256, 0, stream>>>(hist1, hist2, P1, N, P2, M);
    hist_kernel<<<gp, 256, 0, stream>>>(pc1, N, pc2, M, hist1, hist2);
    scan_kernel<<<1, NB, 0, stream>>>(hist1, hist2, start1, start2, cur1, cur2);
    scatter_kernel<<<gp, 256, 0, stream>>>(pc1, N, pc2, M, cur1, cur2,
                                           S1, nrm1, idx1, S2, nrm2, idx2);

    const int maxNM = (N > M) ? N : M;
    dim3 grid((maxNM + QG - 1) / QG, 2, 2);
    minscan_kernel<<<grid, QG, 0, stream>>>(S1, nrm1, idx1, N, S2, nrm2, idx2, M,
                                            start1, start2, P1, P2);

    const int gr = (T + RBLOCK - 1) / RBLOCK;
    reduce1_kernel<<<gr, RBLOCK, 0, stream>>>(P1, N, P2, M, bsum);
    reduce2_kernel<<<1, RBLOCK, 0, stream>>>(bsum, gr, out);
}